// Round 1
// baseline (61.569 us; speedup 1.0000x reference)
//
#include <hip/hip_runtime.h>

// BoxCrossAttention: softmax over a length-1 key axis == 1.0, so the output is
// out[b,c,w,h] = 9 * (vp[b] @ Wo + bo)[c]  with  vp = (mish(y@W1+b1)@W2+b2)[:,512:] @ Wv + bv
// The entire x / conv / unfold / q-projection / scores path is dead code.

__device__ __forceinline__ float mishf(float v) {
    // mish(v) = v * tanh(softplus(v)); softplus(v) = log1p(exp(v)), ~= v for large v
    float sp = (v > 20.0f) ? v : log1pf(expf(v));
    return v * tanhf(sp);
}

// Stage 1: hidden[b][j] = mish(sum_t y[b][t] * W1[t][j] + b1[j]),  b<4, j<1024
__global__ __launch_bounds__(256) void k_hidden(const float* __restrict__ y,
                                                const float* __restrict__ W1,
                                                const float* __restrict__ b1,
                                                float* __restrict__ hidden) {
    int tid = blockIdx.x * 256 + threadIdx.x;   // 0..4095
    int b = tid >> 10, j = tid & 1023;
    const float* yb = y + b * 256;
    float a0 = 0.f, a1 = 0.f, a2 = 0.f, a3 = 0.f;
    for (int t = 0; t < 256; t += 4) {
        a0 = fmaf(yb[t + 0], W1[(t + 0) * 1024 + j], a0);
        a1 = fmaf(yb[t + 1], W1[(t + 1) * 1024 + j], a1);
        a2 = fmaf(yb[t + 2], W1[(t + 2) * 1024 + j], a2);
        a3 = fmaf(yb[t + 3], W1[(t + 3) * 1024 + j], a3);
    }
    float acc = b1[j] + ((a0 + a1) + (a2 + a3));
    hidden[tid] = mishf(acc);
}

// Stage 2: v_raw[b][i2] = sum_i hidden[b][i] * W2[i][512+i2] + b2[512+i2],  b<4, i2<512
// (columns 0..511 of W2 produce k_raw, which is dead)
__global__ __launch_bounds__(256) void k_vraw(const float* __restrict__ hidden,
                                              const float* __restrict__ W2,
                                              const float* __restrict__ b2,
                                              float* __restrict__ v_raw) {
    int tid = blockIdx.x * 256 + threadIdx.x;   // 0..2047
    int b = tid >> 9, i2 = tid & 511;
    const float* hb = hidden + b * 1024;
    const float* w = W2 + 512 + i2;             // column (512+i2), row stride 1024
    float a0 = 0.f, a1 = 0.f, a2 = 0.f, a3 = 0.f;
    for (int i = 0; i < 1024; i += 4) {
        a0 = fmaf(hb[i + 0], w[(size_t)(i + 0) * 1024], a0);
        a1 = fmaf(hb[i + 1], w[(size_t)(i + 1) * 1024], a1);
        a2 = fmaf(hb[i + 2], w[(size_t)(i + 2) * 1024], a2);
        a3 = fmaf(hb[i + 3], w[(size_t)(i + 3) * 1024], a3);
    }
    v_raw[tid] = b2[512 + i2] + ((a0 + a1) + (a2 + a3));
}

// Stage 3: vp[b][d] = v_raw[b] @ Wv[:,d] + bv[d]; o9[b][d'] = 9*(vp[b] @ Wo[:,d'] + bo[d'])
// One block per batch, vp staged in LDS.
__global__ __launch_bounds__(256) void k_o9(const float* __restrict__ v_raw,
                                            const float* __restrict__ Wv,
                                            const float* __restrict__ bv,
                                            const float* __restrict__ Wo,
                                            const float* __restrict__ bo,
                                            float* __restrict__ o9) {
    int b = blockIdx.x, d = threadIdx.x;
    __shared__ float vp_s[256];
    const float* vb = v_raw + b * 512;
    float a0 = 0.f, a1 = 0.f;
    for (int i = 0; i < 512; i += 2) {
        a0 = fmaf(vb[i + 0], Wv[(i + 0) * 256 + d], a0);
        a1 = fmaf(vb[i + 1], Wv[(i + 1) * 256 + d], a1);
    }
    vp_s[d] = bv[d] + a0 + a1;
    __syncthreads();
    float c0 = 0.f, c1 = 0.f;
    for (int i = 0; i < 256; i += 2) {
        c0 = fmaf(vp_s[i + 0], Wo[(i + 0) * 256 + d], c0);
        c1 = fmaf(vp_s[i + 1], Wo[(i + 1) * 256 + d], c1);
    }
    o9[b * 256 + d] = 9.0f * (bo[d] + c0 + c1);
}

// Stage 4: out[b][c][w][h] = o9[b][c] — each (b,c) is 4096 consecutive fp32.
// One block per (b,c); 256 threads x 4 float4 stores = 4096 floats.
__global__ __launch_bounds__(256) void k_bcast(const float* __restrict__ o9,
                                               float4* __restrict__ out) {
    float v = o9[blockIdx.x];
    float4 vv = make_float4(v, v, v, v);
    float4* p = out + (size_t)blockIdx.x * 1024;
    p[threadIdx.x + 0]   = vv;
    p[threadIdx.x + 256] = vv;
    p[threadIdx.x + 512] = vv;
    p[threadIdx.x + 768] = vv;
}

extern "C" void kernel_launch(void* const* d_in, const int* in_sizes, int n_in,
                              void* d_out, int out_size, void* d_ws, size_t ws_size,
                              hipStream_t stream) {
    // setup_inputs order:
    // 0:x 1:y 2:Wp 3:bp 4:W1 5:b1 6:W2 7:b2 8:Wq 9:bq 10:Wk 11:bk 12:Wv 13:bv 14:Wo 15:bo
    const float* y  = (const float*)d_in[1];
    const float* W1 = (const float*)d_in[4];
    const float* b1 = (const float*)d_in[5];
    const float* W2 = (const float*)d_in[6];
    const float* b2 = (const float*)d_in[7];
    const float* Wv = (const float*)d_in[12];
    const float* bv = (const float*)d_in[13];
    const float* Wo = (const float*)d_in[14];
    const float* bo = (const float*)d_in[15];

    float* ws     = (float*)d_ws;
    float* hidden = ws;          // 4096 floats
    float* v_raw  = ws + 4096;   // 2048 floats
    float* o9     = ws + 6144;   // 1024 floats

    k_hidden<<<16,   256, 0, stream>>>(y, W1, b1, hidden);
    k_vraw  <<<8,    256, 0, stream>>>(hidden, W2, b2, v_raw);
    k_o9    <<<4,    256, 0, stream>>>(v_raw, Wv, bv, Wo, bo, o9);
    k_bcast <<<1024, 256, 0, stream>>>(o9, (float4*)d_out);
}

// Round 2
// 20.966 us; speedup vs baseline: 2.9366x; 2.9366x over previous
//
#include <hip/hip_runtime.h>

// BoxCrossAttention: softmax over a length-1 key axis == 1.0, so
// out[b,c,w,h] = 9 * (vp[b] @ Wo + bo)[c],  vp = (mish(y@W1+b1)@W2+b2)[:,512:] @ Wv + bv.
// x / conv / unfold / q / k projections are dead code.
//
// All GEMV stages use in-block split-K: block = (cols x kchunks), coalesced
// weight loads, LDS partial reduction. Final kernel fuses the Wo GEMM with the
// [W*H] broadcast store.

__device__ __forceinline__ float mishf(float v) {
    float sp = (v > 20.0f) ? v : log1pf(expf(v));
    return v * tanhf(sp);
}

// Stage 1: hidden[b][j] = mish(b1[j] + sum_{t<256} y[b][t]*W1[t][j]), j<1024
// grid 64 = 4b x 16 colblocks(64); block 256 = 64 cols x 4 kchunks(64 rows)
__global__ __launch_bounds__(256) void k_hidden(const float* __restrict__ y,
                                                const float* __restrict__ W1,
                                                const float* __restrict__ b1,
                                                float* __restrict__ hidden) {
    int b  = blockIdx.x >> 4;
    int j0 = (blockIdx.x & 15) * 64;
    int t  = threadIdx.x;
    int col = j0 + (t & 63);
    int kc  = t >> 6;                       // 0..3
    __shared__ float y_s[256];
    __shared__ float ps[256];
    y_s[t] = y[b * 256 + t];
    __syncthreads();
    const float* w  = W1 + (size_t)(kc * 64) * 1024 + col;
    const float* ys = y_s + kc * 64;
    float a0 = 0.f, a1 = 0.f, a2 = 0.f, a3 = 0.f;
    for (int r = 0; r < 64; r += 4) {
        a0 = fmaf(ys[r + 0], w[(r + 0) * 1024], a0);
        a1 = fmaf(ys[r + 1], w[(r + 1) * 1024], a1);
        a2 = fmaf(ys[r + 2], w[(r + 2) * 1024], a2);
        a3 = fmaf(ys[r + 3], w[(r + 3) * 1024], a3);
    }
    ps[t] = (a0 + a1) + (a2 + a3);
    __syncthreads();
    if (t < 64) {
        float s = (ps[t] + ps[t + 64]) + (ps[t + 128] + ps[t + 192]);
        hidden[b * 1024 + j0 + t] = mishf(s + b1[j0 + t]);
    }
}

// Stage 2: v_raw[b][c] = b2[512+c] + sum_{i<1024} hidden[b][i]*W2[i][512+c], c<512
// grid 128 = 4b x 32 colblocks(16); block 256 = 16 cols x 16 kchunks(64 rows)
__global__ __launch_bounds__(256) void k_vraw(const float* __restrict__ hidden,
                                              const float* __restrict__ W2,
                                              const float* __restrict__ b2,
                                              float* __restrict__ v_raw) {
    int b  = blockIdx.x >> 5;
    int c0 = (blockIdx.x & 31) * 16;
    int t  = threadIdx.x;
    int col = c0 + (t & 15);
    int kc  = t >> 4;                       // 0..15
    __shared__ float h_s[1024];
    __shared__ float ps[256];
    h_s[t]       = hidden[b * 1024 + t];
    h_s[t + 256] = hidden[b * 1024 + t + 256];
    h_s[t + 512] = hidden[b * 1024 + t + 512];
    h_s[t + 768] = hidden[b * 1024 + t + 768];
    __syncthreads();
    const float* w  = W2 + (size_t)(kc * 64) * 1024 + 512 + col;
    const float* hs = h_s + kc * 64;
    float a0 = 0.f, a1 = 0.f, a2 = 0.f, a3 = 0.f;
    for (int r = 0; r < 64; r += 4) {
        a0 = fmaf(hs[r + 0], w[(size_t)(r + 0) * 1024], a0);
        a1 = fmaf(hs[r + 1], w[(size_t)(r + 1) * 1024], a1);
        a2 = fmaf(hs[r + 2], w[(size_t)(r + 2) * 1024], a2);
        a3 = fmaf(hs[r + 3], w[(size_t)(r + 3) * 1024], a3);
    }
    ps[t] = (a0 + a1) + (a2 + a3);
    __syncthreads();
    if (t < 16) {
        float s = 0.f;
        #pragma unroll
        for (int k = 0; k < 16; ++k) s += ps[t + 16 * k];
        v_raw[b * 512 + c0 + t] = s + b2[512 + c0 + t];
    }
}

// Stage 3: vp[b][d] = bv[d] + sum_{i<512} v_raw[b][i]*Wv[i][d], d<256
// grid 32 = 4b x 8 colblocks(32); block 256 = 32 cols x 8 kchunks(64 rows)
__global__ __launch_bounds__(256) void k_vp(const float* __restrict__ v_raw,
                                            const float* __restrict__ Wv,
                                            const float* __restrict__ bv,
                                            float* __restrict__ vp) {
    int b  = blockIdx.x >> 3;
    int d0 = (blockIdx.x & 7) * 32;
    int t  = threadIdx.x;
    int col = d0 + (t & 31);
    int kc  = t >> 5;                       // 0..7
    __shared__ float v_s[512];
    __shared__ float ps[256];
    v_s[t]       = v_raw[b * 512 + t];
    v_s[t + 256] = v_raw[b * 512 + t + 256];
    __syncthreads();
    const float* w  = Wv + (size_t)(kc * 64) * 256 + col;
    const float* vs = v_s + kc * 64;
    float a0 = 0.f, a1 = 0.f, a2 = 0.f, a3 = 0.f;
    for (int r = 0; r < 64; r += 4) {
        a0 = fmaf(vs[r + 0], w[(r + 0) * 256], a0);
        a1 = fmaf(vs[r + 1], w[(r + 1) * 256], a1);
        a2 = fmaf(vs[r + 2], w[(r + 2) * 256], a2);
        a3 = fmaf(vs[r + 3], w[(r + 3) * 256], a3);
    }
    ps[t] = (a0 + a1) + (a2 + a3);
    __syncthreads();
    if (t < 32) {
        float s = 0.f;
        #pragma unroll
        for (int k = 0; k < 8; ++k) s += ps[t + 32 * k];
        vp[b * 256 + d0 + t] = s + bv[d0 + t];
    }
}

// Stage 4 (fused): block (b,c) computes o9 = 9*(dot(vp[b], Wo[:,c]) + bo[c])
// then broadcasts it over the 4096 contiguous (w,h) slots. grid 1024, block 256.
__global__ __launch_bounds__(256) void k_out(const float* __restrict__ vp,
                                             const float* __restrict__ Wo,
                                             const float* __restrict__ bo,
                                             float4* __restrict__ out) {
    int b = blockIdx.x >> 8;
    int c = blockIdx.x & 255;
    int t = threadIdx.x;
    __shared__ float red[256];
    red[t] = vp[b * 256 + t] * Wo[(size_t)t * 256 + c];
    __syncthreads();
    if (t < 64) {
        float s = (red[t] + red[t + 64]) + (red[t + 128] + red[t + 192]);
        s += __shfl_down(s, 32);
        s += __shfl_down(s, 16);
        s += __shfl_down(s, 8);
        s += __shfl_down(s, 4);
        s += __shfl_down(s, 2);
        s += __shfl_down(s, 1);
        if (t == 0) red[0] = 9.0f * (s + bo[c]);
    }
    __syncthreads();
    float v = red[0];
    float4 vv = make_float4(v, v, v, v);
    float4* p = out + (size_t)blockIdx.x * 1024;
    p[t]       = vv;
    p[t + 256] = vv;
    p[t + 512] = vv;
    p[t + 768] = vv;
}

extern "C" void kernel_launch(void* const* d_in, const int* in_sizes, int n_in,
                              void* d_out, int out_size, void* d_ws, size_t ws_size,
                              hipStream_t stream) {
    // 0:x 1:y 2:Wp 3:bp 4:W1 5:b1 6:W2 7:b2 8:Wq 9:bq 10:Wk 11:bk 12:Wv 13:bv 14:Wo 15:bo
    const float* y  = (const float*)d_in[1];
    const float* W1 = (const float*)d_in[4];
    const float* b1 = (const float*)d_in[5];
    const float* W2 = (const float*)d_in[6];
    const float* b2 = (const float*)d_in[7];
    const float* Wv = (const float*)d_in[12];
    const float* bv = (const float*)d_in[13];
    const float* Wo = (const float*)d_in[14];
    const float* bo = (const float*)d_in[15];

    float* ws     = (float*)d_ws;
    float* hidden = ws;          // 4096 floats
    float* v_raw  = ws + 4096;   // 2048 floats
    float* vp     = ws + 6144;   // 1024 floats

    k_hidden<<<64,   256, 0, stream>>>(y, W1, b1, hidden);
    k_vraw  <<<128,  256, 0, stream>>>(hidden, W2, b2, v_raw);
    k_vp    <<<32,   256, 0, stream>>>(v_raw, Wv, bv, vp);
    k_out   <<<1024, 256, 0, stream>>>(vp, Wo, bo, (float4*)d_out);
}